// Round 2
// baseline (274.971 us; speedup 1.0000x reference)
//
#include <hip/hip_runtime.h>
#include <hip/hip_bf16.h>
#include <math.h>

typedef __attribute__((ext_vector_type(8))) __bf16 bf16x8;
typedef __attribute__((ext_vector_type(4))) float f32x4;

#define IN_DIM 2048
#define NH1 128
#define NH2 64
#define KDIM 1024

__device__ inline f32x4 mfma16(bf16x8 a, bf16x8 b, f32x4 c) {
    return __builtin_amdgcn_mfma_f32_16x16x32_bf16(a, b, c, 0, 0, 0);
}

// ---------------------------------------------------------------------------
// prep: permute W1/W2 into MFMA-fragment order (bf16), pack basis rows with
// c_j = head_w[j] * exp(-||b_j||^2).
// Fragment convention (A and B identical): within a 32-k x 16-col tile,
// lane l, elem e  ->  k = (l>>4)*8 + e , col/row = l&15.
// ---------------------------------------------------------------------------
__global__ void prep_kernel(const float* __restrict__ W1,
                            const float* __restrict__ W2,
                            const float* __restrict__ basis,
                            const float* __restrict__ head_w,
                            __bf16* __restrict__ w1f,
                            __bf16* __restrict__ w2f,
                            float* __restrict__ bp) {
    int idx = blockIdx.x * 256 + threadIdx.x;   // 0 .. 262143
    if (idx < IN_DIM * NH1) {
        // layout: ((ks*8 + c) << 9) + l*8 + e ; ks: 64 steps of K=32
        int ks = idx >> 12;
        int rem = idx & 4095;
        int c = rem >> 9;
        int q = rem & 511;
        int l = q >> 3, e = q & 7;
        int k = ks * 32 + ((l >> 4) << 3) + e;
        int col = (c << 4) + (l & 15);
        w1f[idx] = (__bf16)W1[k * NH1 + col];
    }
    if (idx < NH1 * NH2) {
        // layout: ((c2*4 + kb) << 9) + l*8 + e ; kb: 4 steps of K=32
        int cb = idx >> 9;
        int c2 = cb >> 2, kb = cb & 3;
        int q = idx & 511;
        int l = q >> 3, e = q & 7;
        int k = kb * 32 + ((l >> 4) << 3) + e;
        int col = (c2 << 4) + (l & 15);
        w2f[idx] = (__bf16)W2[k * NH2 + col];
    }
    if (idx < KDIM) {
        const float* b = basis + idx * 5;
        float n2 = b[0]*b[0] + b[1]*b[1] + b[2]*b[2] + b[3]*b[3] + b[4]*b[4];
        float* o = bp + idx * 8;
        o[0] = b[0]; o[1] = b[1]; o[2] = b[2]; o[3] = b[3]; o[4] = b[4];
        o[5] = 1.0f;
        o[6] = head_w[idx] * expf(-n2);   // gamma = 1
        o[7] = 0.0f;
    }
}

// ---------------------------------------------------------------------------
// fused main: per wave: 16 rows (1 MFMA row-group), 4 waves/block = 64 rows.
// 1024 blocks -> 4096 waves -> 4 waves/SIMD for latency hiding.
// Stage 1 uses 2-iteration-ahead register prefetch of the HBM x stream.
// ---------------------------------------------------------------------------

// One K=32 step of GEMM1. A0/A1: current x data (8 floats). If PF_EN, prefetch
// x for k-step KPF into PA0/PA1 (issued before the MFMAs so it overlaps).
#define S1_STEP(A0, A1, KS, PF_EN, PA0, PA1, KPF)                             \
    {                                                                         \
        bf16x8 Af;                                                            \
        Af[0] = (__bf16)A0.x; Af[1] = (__bf16)A0.y;                           \
        Af[2] = (__bf16)A0.z; Af[3] = (__bf16)A0.w;                           \
        Af[4] = (__bf16)A1.x; Af[5] = (__bf16)A1.y;                           \
        Af[6] = (__bf16)A1.z; Af[7] = (__bf16)A1.w;                           \
        if (PF_EN) {                                                          \
            PA0 = *(const f32x4*)(xp + (KPF) * 32);                           \
            PA1 = *(const f32x4*)(xp + (KPF) * 32 + 4);                       \
        }                                                                     \
        const __bf16* wp = wbase + ((size_t)(KS) << 12);                      \
        _Pragma("unroll")                                                     \
        for (int c = 0; c < 8; ++c) {                                         \
            bf16x8 B = *(const bf16x8*)(wp + (c << 9));                       \
            acc[c] = mfma16(Af, B, acc[c]);                                   \
        }                                                                     \
    }

__launch_bounds__(256, 4)
__global__ void fused_main(const float* __restrict__ x,
                           const __bf16* __restrict__ w1f,
                           const float* __restrict__ b1,
                           const __bf16* __restrict__ w2f,
                           const float* __restrict__ b2,
                           const float* __restrict__ W3,
                           const float* __restrict__ b3,
                           const float* __restrict__ conv_k,
                           const float* __restrict__ conv_b,
                           const float* __restrict__ bp,
                           const float* __restrict__ head_b,
                           float* __restrict__ out) {
    __shared__ __bf16 h1s[4][16 * NH1];            // 16 KB, wave-private tiles
    __shared__ __align__(16) float z5s[64][8];     // 2 KB
    __shared__ float psum[4][64];                  // 1 KB

    const int tid = threadIdx.x;
    const int w = __builtin_amdgcn_readfirstlane(tid >> 6);
    const int l = tid & 63;
    const int row0 = blockIdx.x * 64 + w * 16;

    // ---------------- stage 1: h1 = relu(x @ W1 + b1), bf16 MFMA ----------
    f32x4 acc[8];
#pragma unroll
    for (int c = 0; c < 8; ++c) acc[c] = (f32x4){0.f, 0.f, 0.f, 0.f};

    const float* xp = x + (size_t)(row0 + (l & 15)) * IN_DIM + ((l >> 4) << 3);
    const __bf16* wbase = w1f + l * 8;

    // 2-deep rolling A prefetch (statically named buffers)
    f32x4 aA0 = *(const f32x4*)(xp);
    f32x4 aA1 = *(const f32x4*)(xp + 4);
    f32x4 aB0 = *(const f32x4*)(xp + 32);
    f32x4 aB1 = *(const f32x4*)(xp + 36);

    for (int ks = 0; ks < 62; ks += 2) {
        S1_STEP(aA0, aA1, ks,     1, aA0, aA1, ks + 2)
        S1_STEP(aB0, aB1, ks + 1, 1, aB0, aB1, ks + 3)
    }
    S1_STEP(aA0, aA1, 62, 0, aA0, aA1, 0)
    S1_STEP(aB0, aB1, 63, 0, aB0, aB1, 0)

    // epilogue: + b1, relu, bf16, into wave-private LDS tile [16][128]
    float b1v[8];
#pragma unroll
    for (int c = 0; c < 8; ++c) b1v[c] = b1[c * 16 + (l & 15)];
    __bf16* hw1 = &h1s[w][0];
#pragma unroll
    for (int c = 0; c < 8; ++c)
#pragma unroll
        for (int r = 0; r < 4; ++r) {
            int rr = ((l >> 4) << 2) + r;
            int cc = c * 16 + (l & 15);
            hw1[rr * NH1 + cc] = (__bf16)fmaxf(acc[c][r] + b1v[c], 0.f);
        }

    __syncthreads();

    // ---------------- stage 2: h2 = relu(h1 @ W2 + b2), bf16 MFMA ---------
    f32x4 acc2[4];
#pragma unroll
    for (int c2 = 0; c2 < 4; ++c2) acc2[c2] = (f32x4){0.f, 0.f, 0.f, 0.f};

#pragma unroll
    for (int kb = 0; kb < 4; ++kb) {
        bf16x8 A = *(const bf16x8*)&hw1[(l & 15) * NH1 + kb * 32 + ((l >> 4) << 3)];
#pragma unroll
        for (int c2 = 0; c2 < 4; ++c2) {
            bf16x8 B = *(const bf16x8*)(w2f + (((c2 << 2) + kb) << 9) + l * 8);
            acc2[c2] = mfma16(A, B, acc2[c2]);
        }
    }

    // ---------------- stage 3: z = h2 @ W3 + b3 ; conv sigmoid ------------
    float b2v[4];
#pragma unroll
    for (int c2 = 0; c2 < 4; ++c2) b2v[c2] = b2[c2 * 16 + (l & 15)];
    float w3l[4][4];
#pragma unroll
    for (int c2 = 0; c2 < 4; ++c2) {
        f32x4 t = *(const f32x4*)&W3[(c2 * 16 + (l & 15)) * 4];
        w3l[c2][0] = t.x; w3l[c2][1] = t.y; w3l[c2][2] = t.z; w3l[c2][3] = t.w;
    }
    float h2v[4][4];
#pragma unroll
    for (int c2 = 0; c2 < 4; ++c2)
#pragma unroll
        for (int r = 0; r < 4; ++r)
            h2v[c2][r] = fmaxf(acc2[c2][r] + b2v[c2], 0.f);

    float pz[4][4];  // [r][j] partial over this lane's 4 k-columns
#pragma unroll
    for (int r = 0; r < 4; ++r)
#pragma unroll
        for (int j = 0; j < 4; ++j) {
            float s = 0.f;
#pragma unroll
            for (int c2 = 0; c2 < 4; ++c2) s = fmaf(h2v[c2][r], w3l[c2][j], s);
            pz[r][j] = s;
        }
    // reduce over the 16 lanes (l&15) that hold distinct k-columns
#pragma unroll
    for (int off = 1; off < 16; off <<= 1)
#pragma unroll
        for (int r = 0; r < 4; ++r)
#pragma unroll
            for (int j = 0; j < 4; ++j)
                pz[r][j] += __shfl_xor(pz[r][j], off, 64);

    const float ck0 = conv_k[0], ck1 = conv_k[1], ck2 = conv_k[2], ck3 = conv_k[3];
    const float cbv = conv_b[0];
    const float b30 = b3[0], b31 = b3[1], b32 = b3[2], b33 = b3[3];
    const float L2E = 1.44269504088896340736f;

    if ((l & 15) == 0) {
#pragma unroll
        for (int r = 0; r < 4; ++r) {
            int rl = w * 16 + ((l >> 4) << 2) + r;
            float z0 = pz[r][0] + b30;
            float z1 = pz[r][1] + b31;
            float z2 = pz[r][2] + b32;
            float z3 = pz[r][3] + b33;
            float s = fmaf(z0, ck0, fmaf(z1, ck1, fmaf(z2, ck2, fmaf(z3, ck3, cbv))));
            float sg = 1.f / (1.f + expf(-s));
            float n2 = z0*z0 + z1*z1 + z2*z2 + z3*z3 + sg*sg;
            z5s[rl][0] = 2.f * L2E * z0;
            z5s[rl][1] = 2.f * L2E * z1;
            z5s[rl][2] = 2.f * L2E * z2;
            z5s[rl][3] = 2.f * L2E * z3;
            z5s[rl][4] = 2.f * L2E * sg;
            z5s[rl][5] = -L2E * n2;
        }
    }
    __syncthreads();

    // ---------------- stage 4: RBF + head ---------------------------------
    // 64 rows/block; each wave handles a 256-wide chunk of the 1024 basis
    // vectors for ALL 64 rows (lane = row, uniform broadcast basis loads).
    f32x4 za = *(const f32x4*)&z5s[l][0];
    float z4s = z5s[l][4];
    float z5c = z5s[l][5];
    const float* bpp = bp + (size_t)w * 256 * 8;
    float accum = 0.f;
#pragma unroll 4
    for (int j = 0; j < 256; ++j) {
        f32x4 q0 = *(const f32x4*)&bpp[j * 8];
        f32x4 q1 = *(const f32x4*)&bpp[j * 8 + 4];
        float arg = fmaf(za.x, q0.x,
                    fmaf(za.y, q0.y,
                    fmaf(za.z, q0.z,
                    fmaf(za.w, q0.w,
                    fmaf(z4s, q1.x, z5c)))));
        accum = fmaf(q1.z, exp2f(arg), accum);
    }
    psum[w][l] = accum;
    __syncthreads();
    if (w == 0)
        out[blockIdx.x * 64 + l] =
            psum[0][l] + psum[1][l] + psum[2][l] + psum[3][l] + head_b[0];
}

// ---------------------------------------------------------------------------
extern "C" void kernel_launch(void* const* d_in, const int* in_sizes, int n_in,
                              void* d_out, int out_size, void* d_ws, size_t ws_size,
                              hipStream_t stream) {
    const float* x     = (const float*)d_in[0];
    const float* W1    = (const float*)d_in[1];
    const float* b1    = (const float*)d_in[2];
    const float* W2    = (const float*)d_in[3];
    const float* b2    = (const float*)d_in[4];
    const float* W3    = (const float*)d_in[5];
    const float* b3    = (const float*)d_in[6];
    const float* ck    = (const float*)d_in[7];
    const float* cb    = (const float*)d_in[8];
    const float* basis = (const float*)d_in[9];
    const float* hwv   = (const float*)d_in[10];
    const float* hb    = (const float*)d_in[11];

    __bf16* w1f = (__bf16*)d_ws;                                 // 524288 B
    __bf16* w2f = (__bf16*)((char*)d_ws + 524288);               // 16384 B
    float*  bpp = (float*)((char*)d_ws + 524288 + 16384);        // 32768 B

    prep_kernel<<<1024, 256, 0, stream>>>(W1, W2, basis, hwv, w1f, w2f, bpp);
    fused_main<<<1024, 256, 0, stream>>>(x, w1f, b1, w2f, b2, W3, b3, ck, cb,
                                         bpp, hb, (float*)d_out);
}

// Round 3
// 258.971 us; speedup vs baseline: 1.0618x; 1.0618x over previous
//
#include <hip/hip_runtime.h>
#include <hip/hip_bf16.h>
#include <math.h>

typedef __attribute__((ext_vector_type(8))) __bf16 bf16x8;
typedef __attribute__((ext_vector_type(4))) float f32x4;

#define IN_DIM 2048
#define NH1 128
#define NH2 64
#define KDIM 1024

__device__ inline f32x4 mfma16(bf16x8 a, bf16x8 b, f32x4 c) {
    return __builtin_amdgcn_mfma_f32_16x16x32_bf16(a, b, c, 0, 0, 0);
}

// ---------------------------------------------------------------------------
// prep: permute W1/W2 into MFMA-fragment order (bf16), pack basis rows with
// c_j = head_w[j] * exp(-||b_j||^2).
// Fragment convention (A and B identical): within a 32-k x 16-col tile,
// lane l, elem e  ->  k = (l>>4)*8 + e , col/row = l&15.
// ---------------------------------------------------------------------------
__global__ void prep_kernel(const float* __restrict__ W1,
                            const float* __restrict__ W2,
                            const float* __restrict__ basis,
                            const float* __restrict__ head_w,
                            __bf16* __restrict__ w1f,
                            __bf16* __restrict__ w2f,
                            float* __restrict__ bp) {
    int idx = blockIdx.x * 256 + threadIdx.x;   // 0 .. 262143
    if (idx < IN_DIM * NH1) {
        // layout: ((ks*8 + c) << 9) + l*8 + e ; ks: 64 steps of K=32
        int ks = idx >> 12;
        int rem = idx & 4095;
        int c = rem >> 9;
        int q = rem & 511;
        int l = q >> 3, e = q & 7;
        int k = ks * 32 + ((l >> 4) << 3) + e;
        int col = (c << 4) + (l & 15);
        w1f[idx] = (__bf16)W1[k * NH1 + col];
    }
    if (idx < NH1 * NH2) {
        // layout: ((c2*4 + kb) << 9) + l*8 + e ; kb: 4 steps of K=32
        int cb = idx >> 9;
        int c2 = cb >> 2, kb = cb & 3;
        int q = idx & 511;
        int l = q >> 3, e = q & 7;
        int k = kb * 32 + ((l >> 4) << 3) + e;
        int col = (c2 << 4) + (l & 15);
        w2f[idx] = (__bf16)W2[k * NH2 + col];
    }
    if (idx < KDIM) {
        const float* b = basis + idx * 5;
        float n2 = b[0]*b[0] + b[1]*b[1] + b[2]*b[2] + b[3]*b[3] + b[4]*b[4];
        float* o = bp + idx * 8;
        o[0] = b[0]; o[1] = b[1]; o[2] = b[2]; o[3] = b[3]; o[4] = b[4];
        o[5] = 1.0f;
        o[6] = head_w[idx] * expf(-n2);   // gamma = 1
        o[7] = 0.0f;
    }
}

// ---------------------------------------------------------------------------
// fused main. Per wave: 16 rows, barrier-free pipelined stage 1:
//   macro-step = BK 128 floats: 16 rows x 512B contiguous burst -> regs ->
//   cvt bf16 -> wave-private swizzled LDS tile -> MFMA fragments.
//   A issued after B(4m+3) / before B(4m+4) so B-waits never drain A.
//   B (w1f, L2/L3-resident) ping-pong prefetched one k-step ahead.
// ---------------------------------------------------------------------------
__launch_bounds__(256, 3)
__global__ void fused_main(const float* __restrict__ x,
                           const __bf16* __restrict__ w1f,
                           const float* __restrict__ b1,
                           const __bf16* __restrict__ w2f,
                           const float* __restrict__ b2,
                           const float* __restrict__ W3,
                           const float* __restrict__ b3,
                           const float* __restrict__ conv_k,
                           const float* __restrict__ conv_b,
                           const float* __restrict__ bp,
                           const float* __restrict__ head_b,
                           float* __restrict__ out) {
    __shared__ __align__(16) __bf16 a_lds[4][2][2048];  // 32 KB, wave-private
    __shared__ __align__(16) float z5s[64][8];          // 2 KB
    __shared__ float psum[4][64];                       // 1 KB

    const int tid = threadIdx.x;
    const int w = tid >> 6;
    const int l = tid & 63;
    const int r = l & 15;        // fragment row (batch row within wave tile)
    const int j = l >> 4;        // fragment k-group
    const int row0 = blockIdx.x * 64 + w * 16;

    f32x4 acc[8];
#pragma unroll
    for (int c = 0; c < 8; ++c) acc[c] = (f32x4){0.f, 0.f, 0.f, 0.f};

    const float* xrow = x + (size_t)(row0 + r) * IN_DIM + j * 32;
    const __bf16* wB = w1f + l * 8;
    __bf16* As0 = &a_lds[w][0][0];
    __bf16* As1 = &a_lds[w][1][0];

    f32x4 rA[8];
    bf16x8 Bk0[8], Bk1[8];

    // lane's x window for macro M: floats M*128 + j*32 + t*8 .. +8 (t=0..3)
#define LOAD_A(M)                                                             \
    {                                                                         \
        _Pragma("unroll")                                                     \
        for (int t = 0; t < 4; ++t) {                                         \
            rA[2*t]   = *(const f32x4*)(xrow + (M) * 128 + t * 8);            \
            rA[2*t+1] = *(const f32x4*)(xrow + (M) * 128 + t * 8 + 4);        \
        }                                                                     \
    }

    // cvt + swizzled store: chunk c = 4j+t  ->  slot c ^ (r&7)
#define STORE_A(BUF)                                                          \
    {                                                                         \
        _Pragma("unroll")                                                     \
        for (int t = 0; t < 4; ++t) {                                         \
            bf16x8 v;                                                         \
            v[0] = (__bf16)rA[2*t].x;   v[1] = (__bf16)rA[2*t].y;             \
            v[2] = (__bf16)rA[2*t].z;   v[3] = (__bf16)rA[2*t].w;             \
            v[4] = (__bf16)rA[2*t+1].x; v[5] = (__bf16)rA[2*t+1].y;           \
            v[6] = (__bf16)rA[2*t+1].z; v[7] = (__bf16)rA[2*t+1].w;           \
            int cp = (4 * j + t) ^ (r & 7);                                   \
            *(bf16x8*)((BUF) + r * 128 + cp * 8) = v;                         \
        }                                                                     \
    }

#define LOAD_B(T, BV)                                                         \
    {                                                                         \
        _Pragma("unroll")                                                     \
        for (int c = 0; c < 8; ++c)                                           \
            BV[c] = *(const bf16x8*)(wB + ((size_t)(T) << 12) + (c << 9));    \
    }

    // fragment read (matches round-2 k-mapping: k = 32s + 8j + e) + 8 MFMA
#define STEP(BUF, S, BV)                                                      \
    {                                                                         \
        int c0 = (4 * (S) + j) ^ (r & 7);                                     \
        bf16x8 Af = *(const bf16x8*)((BUF) + r * 128 + c0 * 8);               \
        _Pragma("unroll")                                                     \
        for (int c = 0; c < 8; ++c) acc[c] = mfma16(Af, BV[c], acc[c]);       \
    }

    // ---------------- stage 1: h1 = relu(x @ W1 + b1) ---------------------
    LOAD_A(0)
    LOAD_B(0, Bk0)
    STORE_A(As0)

#pragma unroll
    for (int m = 0; m < 16; ++m) {
        __bf16* cur = (m & 1) ? As1 : As0;
        __bf16* nxt = (m & 1) ? As0 : As1;
        LOAD_B(4*m + 1, Bk1)
        STEP(cur, 0, Bk0)
        LOAD_B(4*m + 2, Bk0)
        STEP(cur, 1, Bk1)
        LOAD_B(4*m + 3, Bk1)
        if (m < 15) { LOAD_A(m + 1) }     // after B(4m+3), before B(4m+4)
        STEP(cur, 2, Bk0)
        if (m < 15) { LOAD_B(4*m + 4, Bk0) }
        STEP(cur, 3, Bk1)
        if (m < 15) { STORE_A(nxt) }      // vmcnt(8): leaves B(4m+4) in flight
    }

    // epilogue: + b1, relu, bf16 -> h1 tile (reuse wave's LDS buf0)
    float b1v[8];
#pragma unroll
    for (int c = 0; c < 8; ++c) b1v[c] = b1[c * 16 + r];
    __bf16* hw1 = As0;
#pragma unroll
    for (int c = 0; c < 8; ++c)
#pragma unroll
        for (int rr4 = 0; rr4 < 4; ++rr4) {
            int rr = (j << 2) + rr4;
            int cc = c * 16 + r;
            hw1[rr * NH1 + cc] = (__bf16)fmaxf(acc[c][rr4] + b1v[c], 0.f);
        }
    // wave-private: no barrier needed before stage 2

    // ---------------- stage 2: h2 = relu(h1 @ W2 + b2) --------------------
    f32x4 acc2[4];
#pragma unroll
    for (int c2 = 0; c2 < 4; ++c2) acc2[c2] = (f32x4){0.f, 0.f, 0.f, 0.f};

#pragma unroll
    for (int kb = 0; kb < 4; ++kb) {
        bf16x8 A = *(const bf16x8*)&hw1[r * NH1 + kb * 32 + j * 8];
#pragma unroll
        for (int c2 = 0; c2 < 4; ++c2) {
            bf16x8 B = *(const bf16x8*)(w2f + (((c2 << 2) + kb) << 9) + l * 8);
            acc2[c2] = mfma16(A, B, acc2[c2]);
        }
    }

    // ---------------- stage 3: z = h2 @ W3 + b3 ; conv sigmoid ------------
    float b2v[4];
#pragma unroll
    for (int c2 = 0; c2 < 4; ++c2) b2v[c2] = b2[c2 * 16 + r];
    float w3l[4][4];
#pragma unroll
    for (int c2 = 0; c2 < 4; ++c2) {
        f32x4 t = *(const f32x4*)&W3[(c2 * 16 + r) * 4];
        w3l[c2][0] = t.x; w3l[c2][1] = t.y; w3l[c2][2] = t.z; w3l[c2][3] = t.w;
    }
    float h2v[4][4];
#pragma unroll
    for (int c2 = 0; c2 < 4; ++c2)
#pragma unroll
        for (int rr = 0; rr < 4; ++rr)
            h2v[c2][rr] = fmaxf(acc2[c2][rr] + b2v[c2], 0.f);

    float pz[4][4];  // [rr][jj] partials over this lane's 4 k-columns
#pragma unroll
    for (int rr = 0; rr < 4; ++rr)
#pragma unroll
        for (int jj = 0; jj < 4; ++jj) {
            float s = 0.f;
#pragma unroll
            for (int c2 = 0; c2 < 4; ++c2) s = fmaf(h2v[c2][rr], w3l[c2][jj], s);
            pz[rr][jj] = s;
        }
#pragma unroll
    for (int off = 1; off < 16; off <<= 1)
#pragma unroll
        for (int rr = 0; rr < 4; ++rr)
#pragma unroll
            for (int jj = 0; jj < 4; ++jj)
                pz[rr][jj] += __shfl_xor(pz[rr][jj], off, 64);

    const float ck0 = conv_k[0], ck1 = conv_k[1], ck2 = conv_k[2], ck3 = conv_k[3];
    const float cbv = conv_b[0];
    const float b30 = b3[0], b31 = b3[1], b32 = b3[2], b33 = b3[3];
    const float L2E = 1.44269504088896340736f;

    if (r == 0) {
#pragma unroll
        for (int rr = 0; rr < 4; ++rr) {
            int rl = w * 16 + (j << 2) + rr;
            float z0 = pz[rr][0] + b30;
            float z1 = pz[rr][1] + b31;
            float z2 = pz[rr][2] + b32;
            float z3 = pz[rr][3] + b33;
            float s = fmaf(z0, ck0, fmaf(z1, ck1, fmaf(z2, ck2, fmaf(z3, ck3, cbv))));
            float sg = 1.f / (1.f + expf(-s));
            float n2 = z0*z0 + z1*z1 + z2*z2 + z3*z3 + sg*sg;
            z5s[rl][0] = 2.f * L2E * z0;
            z5s[rl][1] = 2.f * L2E * z1;
            z5s[rl][2] = 2.f * L2E * z2;
            z5s[rl][3] = 2.f * L2E * z3;
            z5s[rl][4] = 2.f * L2E * sg;
            z5s[rl][5] = -L2E * n2;
        }
    }
    __syncthreads();

    // ---------------- stage 4: RBF + head ---------------------------------
    // lane = row (64 rows/block); each wave takes a 256-wide basis chunk.
    f32x4 za = *(const f32x4*)&z5s[l][0];
    float z4s = z5s[l][4];
    float z5c = z5s[l][5];
    const float* bpp = bp + (size_t)w * 256 * 8;
    float accum = 0.f;
#pragma unroll 4
    for (int jb = 0; jb < 256; ++jb) {
        f32x4 q0 = *(const f32x4*)&bpp[jb * 8];
        f32x4 q1 = *(const f32x4*)&bpp[jb * 8 + 4];
        float arg = fmaf(za.x, q0.x,
                    fmaf(za.y, q0.y,
                    fmaf(za.z, q0.z,
                    fmaf(za.w, q0.w,
                    fmaf(z4s, q1.x, z5c)))));
        accum = fmaf(q1.z, exp2f(arg), accum);
    }
    psum[w][l] = accum;
    __syncthreads();
    if (w == 0)
        out[blockIdx.x * 64 + l] =
            psum[0][l] + psum[1][l] + psum[2][l] + psum[3][l] + head_b[0];
}

// ---------------------------------------------------------------------------
extern "C" void kernel_launch(void* const* d_in, const int* in_sizes, int n_in,
                              void* d_out, int out_size, void* d_ws, size_t ws_size,
                              hipStream_t stream) {
    const float* x     = (const float*)d_in[0];
    const float* W1    = (const float*)d_in[1];
    const float* b1    = (const float*)d_in[2];
    const float* W2    = (const float*)d_in[3];
    const float* b2    = (const float*)d_in[4];
    const float* W3    = (const float*)d_in[5];
    const float* b3    = (const float*)d_in[6];
    const float* ck    = (const float*)d_in[7];
    const float* cb    = (const float*)d_in[8];
    const float* basis = (const float*)d_in[9];
    const float* hwv   = (const float*)d_in[10];
    const float* hb    = (const float*)d_in[11];

    __bf16* w1f = (__bf16*)d_ws;                                 // 524288 B
    __bf16* w2f = (__bf16*)((char*)d_ws + 524288);               // 16384 B
    float*  bpp = (float*)((char*)d_ws + 524288 + 16384);        // 32768 B

    prep_kernel<<<1024, 256, 0, stream>>>(W1, W2, basis, hwv, w1f, w2f, bpp);
    fused_main<<<1024, 256, 0, stream>>>(x, w1f, b1, w2f, b2, W3, b3, ck, cb,
                                         bpp, hb, (float*)d_out);
}

// Round 4
// 172.261 us; speedup vs baseline: 1.5962x; 1.5034x over previous
//
#include <hip/hip_runtime.h>
#include <hip/hip_bf16.h>
#include <math.h>

typedef __attribute__((ext_vector_type(8))) __bf16 bf16x8;
typedef __attribute__((ext_vector_type(4))) float f32x4;

#define IN_DIM 2048
#define NH1 128
#define NH2 64
#define KDIM 1024

__device__ inline f32x4 mfma16(bf16x8 a, bf16x8 b, f32x4 c) {
    return __builtin_amdgcn_mfma_f32_16x16x32_bf16(a, b, c, 0, 0, 0);
}

__device__ inline void gld16(const void* g, void* l) {
    __builtin_amdgcn_global_load_lds(
        (const __attribute__((address_space(1))) void*)g,
        (__attribute__((address_space(3))) void*)l, 16, 0, 0);
}

// ---------------------------------------------------------------------------
// prep: permute W1/W2 into MFMA-fragment order (bf16), pack basis rows with
// c_j = head_w[j] * exp(-||b_j||^2).
// Fragment convention (A and B identical): within a 32-k x 16-col tile,
// lane l, elem e  ->  k = (l>>4)*8 + e , col/row = l&15.
// ---------------------------------------------------------------------------
__global__ void prep_kernel(const float* __restrict__ W1,
                            const float* __restrict__ W2,
                            const float* __restrict__ basis,
                            const float* __restrict__ head_w,
                            __bf16* __restrict__ w1f,
                            __bf16* __restrict__ w2f,
                            float* __restrict__ bp) {
    int idx = blockIdx.x * 256 + threadIdx.x;   // 0 .. 262143
    if (idx < IN_DIM * NH1) {
        int ks = idx >> 12;
        int rem = idx & 4095;
        int c = rem >> 9;
        int q = rem & 511;
        int l = q >> 3, e = q & 7;
        int k = ks * 32 + ((l >> 4) << 3) + e;
        int col = (c << 4) + (l & 15);
        w1f[idx] = (__bf16)W1[k * NH1 + col];
    }
    if (idx < NH1 * NH2) {
        int cb = idx >> 9;
        int c2 = cb >> 2, kb = cb & 3;
        int q = idx & 511;
        int l = q >> 3, e = q & 7;
        int k = kb * 32 + ((l >> 4) << 3) + e;
        int col = (c2 << 4) + (l & 15);
        w2f[idx] = (__bf16)W2[k * NH2 + col];
    }
    if (idx < KDIM) {
        const float* b = basis + idx * 5;
        float n2 = b[0]*b[0] + b[1]*b[1] + b[2]*b[2] + b[3]*b[3] + b[4]*b[4];
        float* o = bp + idx * 8;
        o[0] = b[0]; o[1] = b[1]; o[2] = b[2]; o[3] = b[3]; o[4] = b[4];
        o[5] = 1.0f;
        o[6] = head_w[idx] * expf(-n2);   // gamma = 1
        o[7] = 0.0f;
    }
}

// ---------------------------------------------------------------------------
// fused main, T3+T4 structure:
//   block = 4 waves, tile 128 rows x 128 cols, BK=32 (one 16x16x32 k-step).
//   A (x, f32) + B (w1f frags) staged via global_load_lds into a 3-deep LDS
//   ring; stage(t+3) issued at iter t (into the buffer just read), waited
//   with counted vmcnt(12) -> ~3 iterations of prefetch distance.
//   A source addresses pre-XOR-swizzled (chunk ^= row&7) so the linear LDS
//   dest gives conflict-free swizzled ds_read_b128.
// LDS map (73728 B): A ring 3x16K @0; B ring 3x8K @49152;
//   post-loop overlays: h1 4x8K @0; z5s @49152; psum @53248.
// ---------------------------------------------------------------------------
__launch_bounds__(256)
__global__ void fused_main(const float* __restrict__ x,
                           const __bf16* __restrict__ w1f,
                           const float* __restrict__ b1,
                           const __bf16* __restrict__ w2f,
                           const float* __restrict__ b2,
                           const float* __restrict__ W3,
                           const float* __restrict__ b3,
                           const float* __restrict__ conv_k,
                           const float* __restrict__ conv_b,
                           const float* __restrict__ bp,
                           const float* __restrict__ head_b,
                           float* __restrict__ out) {
    __shared__ __align__(16) char smem[73728];

    const int tid = threadIdx.x;
    const int w = tid >> 6;
    const int l = tid & 63;
    const int r = l & 15;        // fragment col/row index
    const int j = l >> 4;        // fragment k-group
    const int row0 = blockIdx.x * 128;

    // ---- staging source pointers (per lane) ------------------------------
    // A: instr q covers rows w*32+q*8 .. +8; lane: row += l>>3, 16B chunk
    //    slot l&7 holds global chunk (l&7)^(l>>3)  (XOR source pre-swizzle).
    const float* aSrc[4];
#pragma unroll
    for (int q = 0; q < 4; ++q)
        aSrc[q] = x + (size_t)(row0 + w * 32 + q * 8 + (l >> 3)) * IN_DIM
                    + (((l & 7) ^ (l >> 3)) << 2);
    // B: linear copy of the 8KB fragment tile; instr i = w*2+q covers 1KB.
    const __bf16* bSrc[2];
#pragma unroll
    for (int q = 0; q < 2; ++q)
        bSrc[q] = w1f + (w * 2 + q) * 512 + l * 8;

#define STAGE_ISSUE(AO, BO)                                                   \
    {                                                                         \
        _Pragma("unroll")                                                     \
        for (int q = 0; q < 4; ++q)                                           \
            gld16(aSrc[q], smem + (AO) + (w * 32 + q * 8) * 128);             \
        _Pragma("unroll")                                                     \
        for (int q = 0; q < 2; ++q)                                           \
            gld16(bSrc[q], smem + (BO) + (w * 2 + q) * 1024);                 \
    }
#define ADVANCE()                                                             \
    {                                                                         \
        _Pragma("unroll") for (int q = 0; q < 4; ++q) aSrc[q] += 32;          \
        _Pragma("unroll") for (int q = 0; q < 2; ++q) bSrc[q] += 4096;        \
    }

    f32x4 acc[2][8];
#pragma unroll
    for (int g = 0; g < 2; ++g)
#pragma unroll
        for (int c = 0; c < 8; ++c) acc[g][c] = (f32x4){0.f, 0.f, 0.f, 0.f};

#define KSTEP(AO, BO)                                                         \
    {                                                                         \
        bf16x8 Bv[8];                                                         \
        _Pragma("unroll")                                                     \
        for (int c = 0; c < 8; ++c)                                           \
            Bv[c] = *(const bf16x8*)(smem + (BO) + (c << 10) + l * 16);       \
        _Pragma("unroll")                                                     \
        for (int g = 0; g < 2; ++g) {                                         \
            const char* ab = smem + (AO) + (w * 32 + g * 16 + r) * 128;       \
            f32x4 f0 = *(const f32x4*)(ab + (((2 * j)     ^ (r & 7)) << 4));  \
            f32x4 f1 = *(const f32x4*)(ab + (((2 * j + 1) ^ (r & 7)) << 4));  \
            bf16x8 Af;                                                        \
            Af[0] = (__bf16)f0.x; Af[1] = (__bf16)f0.y;                       \
            Af[2] = (__bf16)f0.z; Af[3] = (__bf16)f0.w;                       \
            Af[4] = (__bf16)f1.x; Af[5] = (__bf16)f1.y;                       \
            Af[6] = (__bf16)f1.z; Af[7] = (__bf16)f1.w;                       \
            _Pragma("unroll")                                                 \
            for (int c = 0; c < 8; ++c)                                       \
                acc[g][c] = mfma16(Af, Bv[c], acc[g][c]);                     \
        }                                                                     \
    }

    // ---- prologue: fill the 3-deep ring ----------------------------------
    STAGE_ISSUE(0, 49152)      ADVANCE()
    STAGE_ISSUE(16384, 57344)  ADVANCE()
    STAGE_ISSUE(32768, 65536)  ADVANCE()
    asm volatile("s_waitcnt vmcnt(12)" ::: "memory");   // stage(0) done
    __builtin_amdgcn_s_barrier();
    __builtin_amdgcn_sched_barrier(0);

    unsigned aoff = 0, boff = 49152;
    // ---- main K-loop: t = 0..60 stage t+3; 61/62/63 drain ----------------
#pragma unroll 1
    for (int t = 0; t < 61; ++t) {
        KSTEP(aoff, boff)
        STAGE_ISSUE(aoff, boff)          // stage(t+3) into buffer just read
        ADVANCE()
        asm volatile("s_waitcnt vmcnt(12)" ::: "memory");  // stage(t+1) done
        __builtin_amdgcn_s_barrier();
        __builtin_amdgcn_sched_barrier(0);
        aoff = (aoff == 32768u) ? 0u : aoff + 16384u;
        boff = (boff == 65536u) ? 49152u : boff + 8192u;
    }
    KSTEP(aoff, boff)                                       // t = 61
    asm volatile("s_waitcnt vmcnt(6)" ::: "memory");
    __builtin_amdgcn_s_barrier();
    __builtin_amdgcn_sched_barrier(0);
    aoff = (aoff == 32768u) ? 0u : aoff + 16384u;
    boff = (boff == 65536u) ? 49152u : boff + 8192u;
    KSTEP(aoff, boff)                                       // t = 62
    asm volatile("s_waitcnt vmcnt(0)" ::: "memory");
    __builtin_amdgcn_s_barrier();
    __builtin_amdgcn_sched_barrier(0);
    aoff = (aoff == 32768u) ? 0u : aoff + 16384u;
    boff = (boff == 65536u) ? 49152u : boff + 8192u;
    KSTEP(aoff, boff)                                       // t = 63

    __syncthreads();   // everyone done reading the ring; safe to overlay

    // ---- epilogue: + b1, relu, bf16 -> wave-private h1 tile --------------
    float b1v[8];
#pragma unroll
    for (int c = 0; c < 8; ++c) b1v[c] = b1[c * 16 + r];
    __bf16* hw1 = (__bf16*)(smem + w * 8192);
#pragma unroll
    for (int c = 0; c < 8; ++c)
#pragma unroll
        for (int g = 0; g < 2; ++g)
#pragma unroll
            for (int rr = 0; rr < 4; ++rr)
                hw1[(g * 16 + j * 4 + rr) * NH1 + c * 16 + r] =
                    (__bf16)fmaxf(acc[g][c][rr] + b1v[c], 0.f);

    // ---- stage 2: h2 = relu(h1 @ W2 + b2), wave-private ------------------
    f32x4 acc2[2][4];
#pragma unroll
    for (int g = 0; g < 2; ++g)
#pragma unroll
        for (int c2 = 0; c2 < 4; ++c2) acc2[g][c2] = (f32x4){0.f, 0.f, 0.f, 0.f};

#pragma unroll
    for (int kb = 0; kb < 4; ++kb) {
        bf16x8 A0 = *(const bf16x8*)&hw1[r * NH1 + kb * 32 + j * 8];
        bf16x8 A1 = *(const bf16x8*)&hw1[(16 + r) * NH1 + kb * 32 + j * 8];
#pragma unroll
        for (int c2 = 0; c2 < 4; ++c2) {
            bf16x8 B = *(const bf16x8*)(w2f + (((c2 << 2) + kb) << 9) + l * 8);
            acc2[0][c2] = mfma16(A0, B, acc2[0][c2]);
            acc2[1][c2] = mfma16(A1, B, acc2[1][c2]);
        }
    }

    // ---- stage 3: z = h2 @ W3 + b3 ; conv sigmoid ------------------------
    float b2v[4];
#pragma unroll
    for (int c2 = 0; c2 < 4; ++c2) b2v[c2] = b2[c2 * 16 + r];
    float w3l[4][4];
#pragma unroll
    for (int c2 = 0; c2 < 4; ++c2) {
        f32x4 t = *(const f32x4*)&W3[(c2 * 16 + r) * 4];
        w3l[c2][0] = t.x; w3l[c2][1] = t.y; w3l[c2][2] = t.z; w3l[c2][3] = t.w;
    }
    float h2v[2][4][4];
#pragma unroll
    for (int g = 0; g < 2; ++g)
#pragma unroll
        for (int c2 = 0; c2 < 4; ++c2)
#pragma unroll
            for (int rr = 0; rr < 4; ++rr)
                h2v[g][c2][rr] = fmaxf(acc2[g][c2][rr] + b2v[c2], 0.f);

    float pz[2][4][4];
#pragma unroll
    for (int g = 0; g < 2; ++g)
#pragma unroll
        for (int rr = 0; rr < 4; ++rr)
#pragma unroll
            for (int jj = 0; jj < 4; ++jj) {
                float s = 0.f;
#pragma unroll
                for (int c2 = 0; c2 < 4; ++c2)
                    s = fmaf(h2v[g][c2][rr], w3l[c2][jj], s);
                pz[g][rr][jj] = s;
            }
#pragma unroll
    for (int off = 1; off < 16; off <<= 1)
#pragma unroll
        for (int g = 0; g < 2; ++g)
#pragma unroll
            for (int rr = 0; rr < 4; ++rr)
#pragma unroll
                for (int jj = 0; jj < 4; ++jj)
                    pz[g][rr][jj] += __shfl_xor(pz[g][rr][jj], off, 64);

    const float ck0 = conv_k[0], ck1 = conv_k[1], ck2 = conv_k[2], ck3 = conv_k[3];
    const float cbv = conv_b[0];
    const float b30 = b3[0], b31 = b3[1], b32 = b3[2], b33 = b3[3];
    const float L2E = 1.44269504088896340736f;

    float (*z5s)[8] = (float(*)[8])(smem + 49152);
    float* psum = (float*)(smem + 53248);

    if (r == 0) {
#pragma unroll
        for (int g = 0; g < 2; ++g)
#pragma unroll
            for (int rr = 0; rr < 4; ++rr) {
                int rl = w * 32 + g * 16 + (j << 2) + rr;
                float z0 = pz[g][rr][0] + b30;
                float z1 = pz[g][rr][1] + b31;
                float z2 = pz[g][rr][2] + b32;
                float z3 = pz[g][rr][3] + b33;
                float s = fmaf(z0, ck0, fmaf(z1, ck1, fmaf(z2, ck2, fmaf(z3, ck3, cbv))));
                float sg = 1.f / (1.f + expf(-s));
                float n2 = z0*z0 + z1*z1 + z2*z2 + z3*z3 + sg*sg;
                z5s[rl][0] = 2.f * L2E * z0;
                z5s[rl][1] = 2.f * L2E * z1;
                z5s[rl][2] = 2.f * L2E * z2;
                z5s[rl][3] = 2.f * L2E * z3;
                z5s[rl][4] = 2.f * L2E * sg;
                z5s[rl][5] = -L2E * n2;
            }
    }
    __syncthreads();

    // ---- stage 4: RBF + head (128 rows, 2 half-splits of 512 basis) ------
    const int row = tid & 127;
    const int half = tid >> 7;
    f32x4 za = *(const f32x4*)&z5s[row][0];
    float z4s = z5s[row][4];
    float z5c = z5s[row][5];
    const float* bpp = bp + (size_t)half * 512 * 8;
    float accum = 0.f;
#pragma unroll 4
    for (int jb = 0; jb < 512; ++jb) {
        f32x4 q0 = *(const f32x4*)&bpp[jb * 8];
        f32x4 q1 = *(const f32x4*)&bpp[jb * 8 + 4];
        float arg = fmaf(za.x, q0.x,
                    fmaf(za.y, q0.y,
                    fmaf(za.z, q0.z,
                    fmaf(za.w, q0.w,
                    fmaf(z4s, q1.x, z5c)))));
        accum = fmaf(q1.z, exp2f(arg), accum);
    }
    if (half) psum[row] = accum;
    __syncthreads();
    if (!half) out[blockIdx.x * 128 + row] = accum + psum[row] + head_b[0];
}

// ---------------------------------------------------------------------------
extern "C" void kernel_launch(void* const* d_in, const int* in_sizes, int n_in,
                              void* d_out, int out_size, void* d_ws, size_t ws_size,
                              hipStream_t stream) {
    const float* x     = (const float*)d_in[0];
    const float* W1    = (const float*)d_in[1];
    const float* b1    = (const float*)d_in[2];
    const float* W2    = (const float*)d_in[3];
    const float* b2    = (const float*)d_in[4];
    const float* W3    = (const float*)d_in[5];
    const float* b3    = (const float*)d_in[6];
    const float* ck    = (const float*)d_in[7];
    const float* cb    = (const float*)d_in[8];
    const float* basis = (const float*)d_in[9];
    const float* hwv   = (const float*)d_in[10];
    const float* hb    = (const float*)d_in[11];

    __bf16* w1f = (__bf16*)d_ws;                                 // 524288 B
    __bf16* w2f = (__bf16*)((char*)d_ws + 524288);               // 16384 B
    float*  bpp = (float*)((char*)d_ws + 524288 + 16384);        // 32768 B

    prep_kernel<<<1024, 256, 0, stream>>>(W1, W2, basis, hwv, w1f, w2f, bpp);
    fused_main<<<512, 256, 0, stream>>>(x, w1f, b1, w2f, b2, W3, b3, ck, cb,
                                        bpp, hb, (float*)d_out);
}